// Round 9
// baseline (6046.105 us; speedup 1.0000x reference)
//
#include <hip/hip_runtime.h>
#include <cstdint>

typedef unsigned short u16;
typedef __attribute__((ext_vector_type(8))) short short8;
typedef __attribute__((ext_vector_type(4))) short short4v;
typedef __attribute__((ext_vector_type(16))) float floatx16;

__device__ __forceinline__ u16 f2bf(float f) {
    unsigned u = __float_as_uint(f);
    return (u16)((u + 0x7FFFu + ((u >> 16) & 1u)) >> 16);  // RNE
}
__device__ __forceinline__ float bf2f(u16 h) {
    return __uint_as_float(((unsigned)h) << 16);
}

__device__ __forceinline__ void gload16(u16* lds, const u16* g) {
    __builtin_amdgcn_global_load_lds(
        (const __attribute__((address_space(1))) unsigned*)g,
        (__attribute__((address_space(3))) unsigned*)lds,
        16, 0, 0);
}

#define CFENCE asm volatile("" ::: "memory")
#define MFMA32(a, b, c) __builtin_amdgcn_mfma_f32_32x32x16_bf16(a, b, c, 0, 0, 0)

// ---------------- elementwise f32 -> bf16 cast (vectorized) ----------------
__global__ void cast_kernel(const float* __restrict__ in, u16* __restrict__ out, int n4) {
    int stride = gridDim.x * blockDim.x;
    for (int i = blockIdx.x * blockDim.x + threadIdx.x; i < n4; i += stride) {
        float4 v = ((const float4*)in)[i];
        short4v o;
        o[0] = (short)f2bf(v.x);
        o[1] = (short)f2bf(v.y);
        o[2] = (short)f2bf(v.z);
        o[3] = (short)f2bf(v.w);
        ((short4v*)out)[i] = o;
    }
}

// ------------- emb [32000][4096] f32 -> Et [4096][32000] bf16 --------------
__global__ void transpose_cast(const float* __restrict__ E, u16* __restrict__ Et) {
    __shared__ u16 t[32][34];
    int bx = blockIdx.x, by = blockIdx.y;
    int x = threadIdx.x, y = threadIdx.y;
    long long c = (long long)bx * 32 + x;
    long long r0 = (long long)by * 32;
#pragma unroll
    for (int i = y; i < 32; i += 8)
        t[x][i] = f2bf(E[(r0 + i) * 4096 + c]);
    __syncthreads();
    int v = by * 32 + x;
#pragma unroll
    for (int i = y; i < 32; i += 8)
        Et[(long long)(bx * 32 + i) * 32000 + v] = t[i][x];
}

// ---------------- row sums of P (bf16) -> l (f32), deterministic -----------
__global__ void rowsum_kernel(const u16* __restrict__ P, float* __restrict__ l, int V) {
    long long base = (long long)blockIdx.x * V;
    const short8* p8 = (const short8*)(P + base);
    int n8 = V >> 3;
    float s = 0.f;
    for (int c = threadIdx.x; c < n8; c += blockDim.x) {
        short8 v = p8[c];
#pragma unroll
        for (int j = 0; j < 8; ++j) s += bf2f((u16)v[j]);
    }
#pragma unroll
    for (int off = 32; off > 0; off >>= 1) s += __shfl_down(s, off, 64);
    __shared__ float red[4];
    if ((threadIdx.x & 63) == 0) red[threadIdx.x >> 6] = s;
    __syncthreads();
    if (threadIdx.x == 0) l[blockIdx.x] = red[0] + red[1] + red[2] + red[3];
}

// ===== 256x256 NT GEMM, 32x32x16 MFMA, K-sliced phases (8 indep chains) =====
// C[M][N] = A[M][K]*B[N][K]^T. 8 waves (2Mx4N); per wave 128x64 out =
// acc[4 mt][2 nt] floatx16. BK=64, 2-tile dbuf; LDS [buf][op][kHalf][256][32]
// bf16 = 128 KiB. kHalf h covers k = h*32..h*32+31 (all 256 rows).
// 16B-chunk swizzle: LDS[r][slot] = G[r][slot ^ ((r>>1)&3)] (write side uses
// pre-swizzled global source; read side XORs the same mask).
//
// Per tile t (d=t&1), phase k-order 32,48,0,16 so each phase's frags come
// from the half staged earliest:
//  p0(k=32): stage kh1(t+1)->d^1 [4 gloads]; MFMA p0 ; reload frags p1 (d,kh1,^16)
//  p1(k=48): stage kh0(t+1)->d^1 [4]; vmcnt(8: keep t+1's 8, retire kh0(t));
//            lgkm(0); B1; MFMA p1 ; reload frags p2 (d,kh0)
//  p2(k= 0): MFMA p2 ; reload frags p3 (d,kh0,^16)
//  p3(k=16): vmcnt(4: retire kh1(t+1), keep kh0(t+1)); lgkm(0); B2;
//            MFMA p3 ; reload frags p0' (d^1,kh1)
// Hazards: B1 publishes kh0(t) (staged t-1/p1) + guards stages into d^1-kh0
// (old reads of d^1-kh0 = t-1's p2/p3 frags, consumed pre-B2(t-1)). B2
// publishes kh1(t+1) + guards t+1/p0 stages into (d,kh1) (reads of (d,kh1) =
// p0/p1 frags, consumed by p1 MFMAs pre-B2). vmcnt precedes each barrier so
// retirement is globally ordered (per-wave vmcnt + barrier = all waves).
// EP=0: store exp(C+bias[col]) bf16.  EP=1: store C/rowsum[row] f32.

template <int EP>
__global__ __launch_bounds__(512, 2)
void gemmK(const u16* __restrict__ A, const u16* __restrict__ B,
           int M, int N, int K,
           const float* __restrict__ bias, u16* __restrict__ Pout,
           const float* __restrict__ rsum, float* __restrict__ Cout) {
    __shared__ u16 lds[2][2][2][256][32];
    const int tid = threadIdx.x;
    const int w = tid >> 6, lane = tid & 63;
    const int wm = w >> 2, wn = w & 3;
    const int l31 = lane & 31, kh = lane >> 5;

    int tm, tn;
    const int nTm = M >> 8;
    if (gridDim.x == 256) {            // GEMM2: 4tm x 8tn per XCD
        const int x = blockIdx.x & 7, wgx = blockIdx.x >> 3;
        tm = (x & 3) * 4 + (wgx & 3);
        tn = (x >> 2) * 8 + (wgx >> 2);
    } else {                           // chunked XCD swizzle, tm-fastest
        const int q = gridDim.x >> 3;
        const int wg = (blockIdx.x & 7) * q + (blockIdx.x >> 3);
        tm = wg % nTm;
        tn = wg / nTm;
    }

    const u16* Abase = A + (long long)tm * 256 * K;
    const u16* Bbase = B + (long long)tn * 256 * K;
    const int NT = K >> 6;

    // frag read element offsets within a kHalf block, chunk-base cb=0:
    // off = R*32 + ((kh ^ ((R>>1)&3)) * 8);  cb=2 variant = off ^ 16
    unsigned offA[4], offB[2];
#pragma unroll
    for (int mt = 0; mt < 4; ++mt) {
        int R = wm * 128 + mt * 32 + l31;
        offA[mt] = (unsigned)(R * 32 + ((kh ^ ((R >> 1) & 3)) << 3));
    }
#pragma unroll
    for (int nt = 0; nt < 2; ++nt) {
        int R = wn * 64 + nt * 32 + l31;
        offB[nt] = (unsigned)(R * 32 + ((kh ^ ((R >> 1) & 3)) << 3));
    }

    // stage source pointers [kHalf][i]: wave w stages rows w*32..w*32+31
    const u16 *pA[2][2], *pB[2][2];
#pragma unroll
    for (int i = 0; i < 2; ++i) {
        int r = w * 32 + i * 16 + (lane >> 2);
        int gc = (lane & 3) ^ ((r >> 1) & 3);
        pA[0][i] = Abase + (long long)r * K + gc * 8;
        pA[1][i] = pA[0][i] + 32;
        pB[0][i] = Bbase + (long long)r * K + gc * 8;
        pB[1][i] = pB[0][i] + 32;
    }

    floatx16 acc[4][2] = {};
    short8 af[4], bf[2];

    // ---- prologue: stage tile0 (8 gloads); drain; preload p0 frags ----
#pragma unroll
    for (int i = 0; i < 2; ++i) gload16((u16*)&lds[0][0][1][w * 32 + i * 16][0], pA[1][i]);
#pragma unroll
    for (int i = 0; i < 2; ++i) gload16((u16*)&lds[0][1][1][w * 32 + i * 16][0], pB[1][i]);
#pragma unroll
    for (int i = 0; i < 2; ++i) gload16((u16*)&lds[0][0][0][w * 32 + i * 16][0], pA[0][i]);
#pragma unroll
    for (int i = 0; i < 2; ++i) gload16((u16*)&lds[0][1][0][w * 32 + i * 16][0], pB[0][i]);
    asm volatile("s_waitcnt vmcnt(0)" ::: "memory");
    __builtin_amdgcn_s_barrier();
    CFENCE;
#pragma unroll
    for (int mt = 0; mt < 4; ++mt)
        af[mt] = *(const short8*)(&lds[0][0][1][0][0] + offA[mt]);
#pragma unroll
    for (int nt = 0; nt < 2; ++nt)
        bf[nt] = *(const short8*)(&lds[0][1][1][0][0] + offB[nt]);
#pragma unroll
    for (int i = 0; i < 2; ++i) {
        pA[0][i] += 64; pA[1][i] += 64; pB[0][i] += 64; pB[1][i] += 64;
    }

    for (int t = 0; t < NT; ++t) {
        const int d = t & 1;
        const bool nx = (t + 1 < NT);

        // ---- p0 (k=32): stage kh1(t+1); MFMA; reload p1 frags (d,kh1,^16)
        if (nx) {
            gload16((u16*)&lds[d ^ 1][0][1][w * 32][0], pA[1][0]);
            gload16((u16*)&lds[d ^ 1][0][1][w * 32 + 16][0], pA[1][1]);
            gload16((u16*)&lds[d ^ 1][1][1][w * 32][0], pB[1][0]);
            gload16((u16*)&lds[d ^ 1][1][1][w * 32 + 16][0], pB[1][1]);
        }
        __builtin_amdgcn_s_setprio(1);
#pragma unroll
        for (int mt = 0; mt < 4; ++mt) {
            acc[mt][0] = MFMA32(af[mt], bf[0], acc[mt][0]);
            acc[mt][1] = MFMA32(af[mt], bf[1], acc[mt][1]);
            af[mt] = *(const short8*)(&lds[d][0][1][0][0] + (offA[mt] ^ 16u));
        }
        bf[0] = *(const short8*)(&lds[d][1][1][0][0] + (offB[0] ^ 16u));
        bf[1] = *(const short8*)(&lds[d][1][1][0][0] + (offB[1] ^ 16u));
        __builtin_amdgcn_s_setprio(0);
        CFENCE;

        // ---- p1 (k=48): stage kh0(t+1); vmcnt; B1; MFMA; reload p2 (d,kh0)
        if (nx) {
            gload16((u16*)&lds[d ^ 1][0][0][w * 32][0], pA[0][0]);
            gload16((u16*)&lds[d ^ 1][0][0][w * 32 + 16][0], pA[0][1]);
            gload16((u16*)&lds[d ^ 1][1][0][w * 32][0], pB[0][0]);
            gload16((u16*)&lds[d ^ 1][1][0][w * 32 + 16][0], pB[0][1]);
            asm volatile("s_waitcnt vmcnt(8)" ::: "memory");
        } else {
            asm volatile("s_waitcnt vmcnt(0)" ::: "memory");
        }
        asm volatile("s_waitcnt lgkmcnt(0)" ::: "memory");
        __builtin_amdgcn_s_barrier();   // B1: publishes kh0(t)
        __builtin_amdgcn_sched_barrier(0);
        CFENCE;
        __builtin_amdgcn_s_setprio(1);
#pragma unroll
        for (int mt = 0; mt < 4; ++mt) {
            acc[mt][0] = MFMA32(af[mt], bf[0], acc[mt][0]);
            acc[mt][1] = MFMA32(af[mt], bf[1], acc[mt][1]);
            af[mt] = *(const short8*)(&lds[d][0][0][0][0] + offA[mt]);
        }
        bf[0] = *(const short8*)(&lds[d][1][0][0][0] + offB[0]);
        bf[1] = *(const short8*)(&lds[d][1][0][0][0] + offB[1]);
        __builtin_amdgcn_s_setprio(0);
        CFENCE;

        // ---- p2 (k=0): MFMA; reload p3 frags (d,kh0,^16) ----
        __builtin_amdgcn_s_setprio(1);
#pragma unroll
        for (int mt = 0; mt < 4; ++mt) {
            acc[mt][0] = MFMA32(af[mt], bf[0], acc[mt][0]);
            acc[mt][1] = MFMA32(af[mt], bf[1], acc[mt][1]);
            af[mt] = *(const short8*)(&lds[d][0][0][0][0] + (offA[mt] ^ 16u));
        }
        bf[0] = *(const short8*)(&lds[d][1][0][0][0] + (offB[0] ^ 16u));
        bf[1] = *(const short8*)(&lds[d][1][0][0][0] + (offB[1] ^ 16u));
        __builtin_amdgcn_s_setprio(0);
        CFENCE;

        // ---- p3 (k=16): vmcnt; B2; MFMA; reload p0' frags (d^1,kh1) ----
        if (nx) asm volatile("s_waitcnt vmcnt(4)" ::: "memory");
        asm volatile("s_waitcnt lgkmcnt(0)" ::: "memory");
        __builtin_amdgcn_s_barrier();   // B2: publishes kh1(t+1)
        __builtin_amdgcn_sched_barrier(0);
        CFENCE;
        __builtin_amdgcn_s_setprio(1);
        if (nx) {
#pragma unroll
            for (int mt = 0; mt < 4; ++mt) {
                acc[mt][0] = MFMA32(af[mt], bf[0], acc[mt][0]);
                acc[mt][1] = MFMA32(af[mt], bf[1], acc[mt][1]);
                af[mt] = *(const short8*)(&lds[d ^ 1][0][1][0][0] + offA[mt]);
            }
            bf[0] = *(const short8*)(&lds[d ^ 1][1][1][0][0] + offB[0]);
            bf[1] = *(const short8*)(&lds[d ^ 1][1][1][0][0] + offB[1]);
        } else {
#pragma unroll
            for (int mt = 0; mt < 4; ++mt) {
                acc[mt][0] = MFMA32(af[mt], bf[0], acc[mt][0]);
                acc[mt][1] = MFMA32(af[mt], bf[1], acc[mt][1]);
            }
        }
        __builtin_amdgcn_s_setprio(0);
#pragma unroll
        for (int i = 0; i < 2; ++i) {
            pA[0][i] += 64; pA[1][i] += 64; pB[0][i] += 64; pB[1][i] += 64;
        }
        CFENCE;
    }

    // ---- epilogue: 32x32 C/D layout (R6-verified):
    //      col = lane&31, row = (reg&3) + 8*(reg>>2) + 4*(lane>>5) ----
    const int rBase = tm * 256 + wm * 128;
    const int cBase = tn * 256 + wn * 64;
#pragma unroll
    for (int mt = 0; mt < 4; ++mt) {
#pragma unroll
        for (int nt = 0; nt < 2; ++nt) {
            const int col = cBase + nt * 32 + l31;
            if (EP == 0) {
                float bv = bias[col];
#pragma unroll
                for (int reg = 0; reg < 16; ++reg) {
                    int row = rBase + mt * 32 + (reg & 3) + 8 * (reg >> 2) + 4 * kh;
                    Pout[(long long)row * N + col] = f2bf(__expf(acc[mt][nt][reg] + bv));
                }
            } else {
#pragma unroll
                for (int reg = 0; reg < 16; ++reg) {
                    int row = rBase + mt * 32 + (reg & 3) + 8 * (reg >> 2) + 4 * kh;
                    Cout[(long long)row * N + col] = acc[mt][nt][reg] * (1.0f / rsum[row]);
                }
            }
        }
    }
}

extern "C" void kernel_launch(void* const* d_in, const int* in_sizes, int n_in,
                              void* d_out, int out_size, void* d_ws, size_t ws_size,
                              hipStream_t stream) {
    const float* x = (const float*)d_in[0];   // [2,2048,1024]
    const float* W = (const float*)d_in[1];   // [32000,1024]
    const float* b = (const float*)d_in[2];   // [32000]
    const float* E = (const float*)d_in[3];   // [32000,4096]
    float* out = (float*)d_out;               // [2,2048,4096]

    const int M = 4096, K1 = 1024, V = 32000, N2 = 4096;

    char* ws = (char*)d_ws;
    size_t off = 0;
    u16* xb = (u16*)(ws + off); off += (size_t)M * K1 * 2;
    u16* Wb = (u16*)(ws + off); off += (size_t)V * K1 * 2;
    u16* Et = (u16*)(ws + off); off += (size_t)N2 * V * 2;
    u16* P  = (u16*)(ws + off); off += (size_t)M * V * 2;
    float* l = (float*)(ws + off); off += (size_t)M * 4;

    cast_kernel<<<2048, 256, 0, stream>>>(x, xb, M * K1 / 4);
    cast_kernel<<<2048, 256, 0, stream>>>(W, Wb, V * K1 / 4);
    transpose_cast<<<dim3(N2 / 32, V / 32), dim3(32, 8), 0, stream>>>(E, Et);
    // GEMM1: [4096 x 32000 x 1024] -> P = exp(x@W^T + b), bf16
    gemmK<0><<<(M / 256) * (V / 256), 512, 0, stream>>>(xb, Wb, M, V, K1, b, P, nullptr, nullptr);
    rowsum_kernel<<<M, 256, 0, stream>>>(P, l, V);
    // GEMM2: [4096 x 4096 x 32000] -> out = (P/l) @ Et^T, f32
    gemmK<1><<<(M / 256) * (N2 / 256), 512, 0, stream>>>(P, Et, M, N2, V, nullptr, nullptr, l, out);
}

// Round 12
// 1422.627 us; speedup vs baseline: 4.2500x; 4.2500x over previous
//
#include <hip/hip_runtime.h>
#include <cstdint>

typedef unsigned short u16;
typedef __attribute__((ext_vector_type(8))) short short8;
typedef __attribute__((ext_vector_type(4))) short short4v;
typedef __attribute__((ext_vector_type(4))) float floatx4;

__device__ __forceinline__ u16 f2bf(float f) {
    unsigned u = __float_as_uint(f);
    return (u16)((u + 0x7FFFu + ((u >> 16) & 1u)) >> 16);  // RNE
}
__device__ __forceinline__ float bf2f(u16 h) {
    return __uint_as_float(((unsigned)h) << 16);
}

__device__ __forceinline__ void gload16(u16* lds, const u16* g) {
    __builtin_amdgcn_global_load_lds(
        (const __attribute__((address_space(1))) unsigned*)g,
        (__attribute__((address_space(3))) unsigned*)lds,
        16, 0, 0);
}

#define CFENCE asm volatile("" ::: "memory")
#define MFMA16(a, b, c) __builtin_amdgcn_mfma_f32_16x16x32_bf16(a, b, c, 0, 0, 0)

// ---------------- elementwise f32 -> bf16 cast (vectorized) ----------------
__global__ void cast_kernel(const float* __restrict__ in, u16* __restrict__ out, int n4) {
    int stride = gridDim.x * blockDim.x;
    for (int i = blockIdx.x * blockDim.x + threadIdx.x; i < n4; i += stride) {
        float4 v = ((const float4*)in)[i];
        short4v o;
        o[0] = (short)f2bf(v.x);
        o[1] = (short)f2bf(v.y);
        o[2] = (short)f2bf(v.z);
        o[3] = (short)f2bf(v.w);
        ((short4v*)out)[i] = o;
    }
}

// ------- emb [32000][4096] f32 -> Et [4096][32000] bf16, 64x64 tiles -------
// Read: float4/lane (256B segments). Write: short8/lane (128B segments).
__global__ void transpose_cast(const float* __restrict__ E, u16* __restrict__ Et) {
    __shared__ u16 t[64][68];
    const int d0 = blockIdx.x * 64, v0 = blockIdx.y * 64;
    const int tid = threadIdx.x;
    const int lr = tid & 15, rr = tid >> 4;   // 16 col-groups x 16 rows
#pragma unroll
    for (int it = 0; it < 4; ++it) {
        int v = it * 16 + rr;
        float4 e = *(const float4*)&E[(long long)(v0 + v) * 4096 + d0 + lr * 4];
        t[lr * 4 + 0][v] = f2bf(e.x);
        t[lr * 4 + 1][v] = f2bf(e.y);
        t[lr * 4 + 2][v] = f2bf(e.z);
        t[lr * 4 + 3][v] = f2bf(e.w);
    }
    __syncthreads();
    const int lc = tid & 7, rd = tid >> 3;    // 8 col-groups x 32 rows
#pragma unroll
    for (int it = 0; it < 2; ++it) {
        int dd = it * 32 + rd;
        short8 o;
#pragma unroll
        for (int j = 0; j < 8; ++j) o[j] = (short)t[dd][lc * 8 + j];
        *(short8*)&Et[(long long)(d0 + dd) * 32000 + v0 + lc * 8] = o;
    }
}

// ------ combine per-tile row partials: l[row] = sum_tn Lp[tn][row] ---------
__global__ void rowsum2(const float* __restrict__ Lp, float* __restrict__ l,
                        int M, int ntn) {
    int row = blockIdx.x * blockDim.x + threadIdx.x;
    if (row < M) {
        float s = 0.f;
        for (int t = 0; t < ntn; ++t) s += Lp[(long long)t * M + row];
        l[row] = s;
    }
}

// ============ 256x256 NT GEMM, 2-barrier deep-pipelined schedule ===========
// R8 kernel verbatim (840us-verified), plus EP=0 fused row-partial sums:
// per thread sum of its 4 cols/row -> shfl_xor over the 16 col-lanes ->
// LDS combine over the 4 wn waves -> Lp[tn][row] (deterministic, no atomics).
// EP=0: store exp(C+bias[col]) bf16 + Lp partials.  EP=1: C/rowsum[row] f32.

template <int EP>
__global__ __launch_bounds__(512, 2)
void gemm8p(const u16* __restrict__ A, const u16* __restrict__ B,
            int M, int N, int K,
            const float* __restrict__ bias, u16* __restrict__ Pout,
            const float* __restrict__ rsum, float* __restrict__ Cout,
            float* __restrict__ Lp) {
    __shared__ u16 lds[2][2][2][128][64];
    __shared__ float red[4][2][128];
    const int tid = threadIdx.x;
    const int w = tid >> 6, lane = tid & 63;
    const int wm = w >> 2, wn = w & 3;
    const int fRow = lane & 15, fC = lane >> 4;
    const int wBase = w * 1024;  // this wave's stage region (elems)

    int tm, tn;
    const int nTm = M >> 8;
    if (gridDim.x == 256) {            // GEMM2: 4tm x 8tn per XCD
        const int x = blockIdx.x & 7, wgx = blockIdx.x >> 3;
        tm = (x & 3) * 4 + (wgx & 3);
        tn = (x >> 2) * 8 + (wgx >> 2);
    } else {                           // chunked XCD swizzle, tm-fastest
        const int q = gridDim.x >> 3;
        const int wg = (blockIdx.x & 7) * q + (blockIdx.x >> 3);
        tm = wg % nTm;
        tn = wg / nTm;
    }

    const u16* Abase = A + (long long)tm * 256 * K;
    const u16* Bbase = B + (long long)tn * 256 * K;
    const int NT = K >> 6;

    // ---- precomputed fragment read ELEMENT offsets (within a half-tile) ----
    unsigned offA[4][2], offB[2][2];
#pragma unroll
    for (int m = 0; m < 4; ++m)
#pragma unroll
        for (int kk = 0; kk < 2; ++kk) {
            int R = wm * 64 + m * 16 + fRow;
            offA[m][kk] = (unsigned)(R * 64 + (((kk * 4 + fC) ^ ((R >> 1) & 7)) * 8));
        }
#pragma unroll
    for (int n = 0; n < 2; ++n)
#pragma unroll
        for (int kk = 0; kk < 2; ++kk) {
            int R = wn * 32 + n * 16 + fRow;
            offB[n][kk] = (unsigned)(R * 64 + (((kk * 4 + fC) ^ ((R >> 1) & 7)) * 8));
        }

    // ---- precomputed global stage source pointers (advanced +=64/tile) ----
    const u16 *pA0[2], *pA1[2], *pB0[2], *pB1[2];
#pragma unroll
    for (int i = 0; i < 2; ++i) {
        int r = w * 16 + i * 8 + (lane >> 3);
        int gcs = (lane & 7) ^ ((r >> 1) & 7);
        long long rowA = ((r >> 6) << 7) + (r & 63);
        long long rowB = ((r >> 5) << 6) + (r & 31);
        pA0[i] = Abase + rowA * K + gcs * 8;
        pA1[i] = Abase + (rowA + 64) * K + gcs * 8;
        pB0[i] = Bbase + rowB * K + gcs * 8;
        pB1[i] = Bbase + (rowB + 32) * K + gcs * 8;
    }

    floatx4 acc[8][4] = {};
    short8 af[4][2], bf0[2][2], bf1[2][2];

    // ---- prologue: tile0 {A0,B0,B1,A1} + tile1 {A0,B1,A1}; vmcnt(6) ----
#pragma unroll
    for (int i = 0; i < 2; ++i) gload16(&lds[0][0][0][0][0] + wBase + i * 512, pA0[i]);
#pragma unroll
    for (int i = 0; i < 2; ++i) gload16(&lds[0][1][0][0][0] + wBase + i * 512, pB0[i]);
#pragma unroll
    for (int i = 0; i < 2; ++i) gload16(&lds[0][1][1][0][0] + wBase + i * 512, pB1[i]);
#pragma unroll
    for (int i = 0; i < 2; ++i) gload16(&lds[0][0][1][0][0] + wBase + i * 512, pA1[i]);
    if (NT > 1) {
#pragma unroll
        for (int i = 0; i < 2; ++i) gload16(&lds[1][0][0][0][0] + wBase + i * 512, pA0[i] + 64);
#pragma unroll
        for (int i = 0; i < 2; ++i) gload16(&lds[1][1][1][0][0] + wBase + i * 512, pB1[i] + 64);
#pragma unroll
        for (int i = 0; i < 2; ++i) gload16(&lds[1][0][1][0][0] + wBase + i * 512, pA1[i] + 64);
        asm volatile("s_waitcnt vmcnt(6)" ::: "memory");
    } else {
        asm volatile("s_waitcnt vmcnt(0)" ::: "memory");
    }
    __builtin_amdgcn_s_barrier();
    CFENCE;

    // steady-state: at tile t, pB0 -> Bh0(t+1); pA0/pB1/pA1 -> (t+2)
#pragma unroll
    for (int i = 0; i < 2; ++i) {
        pB0[i] += 64;
        pA0[i] += 128;
        pB1[i] += 128;
        pA1[i] += 128;
    }

    // preload af <- Ah0(0), bf1 <- Bh1(0)
#pragma unroll
    for (int m = 0; m < 4; ++m)
#pragma unroll
        for (int kk = 0; kk < 2; ++kk)
            af[m][kk] = *(const short8*)(&lds[0][0][0][0][0] + offA[m][kk]);
#pragma unroll
    for (int n = 0; n < 2; ++n)
#pragma unroll
        for (int kk = 0; kk < 2; ++kk)
            bf1[n][kk] = *(const short8*)(&lds[0][1][1][0][0] + offB[n][kk]);

    for (int t = 0; t < NT; ++t) {
        const int d = t & 1;

        // ---------------- P1 ----------------
#pragma unroll
        for (int n = 0; n < 2; ++n)
#pragma unroll
            for (int kk = 0; kk < 2; ++kk)
                bf0[n][kk] = *(const short8*)(&lds[d][1][0][0][0] + offB[n][kk]);
        if (t + 1 < NT) {
            gload16(&lds[d ^ 1][1][0][0][0] + wBase, pB0[0]);
            gload16(&lds[d ^ 1][1][0][0][0] + wBase + 512, pB0[1]);
        }
        asm volatile("s_waitcnt lgkmcnt(0)" ::: "memory");
        __builtin_amdgcn_sched_barrier(0);
        __builtin_amdgcn_s_setprio(1);
#pragma unroll
        for (int m = 0; m < 4; ++m)
#pragma unroll
            for (int n = 0; n < 2; ++n)
#pragma unroll
                for (int kk = 0; kk < 2; ++kk)
                    acc[m][n] = MFMA16(af[m][kk], bf0[n][kk], acc[m][n]);
        __builtin_amdgcn_s_setprio(0);
        __builtin_amdgcn_s_barrier();   // B1
        CFENCE;

        // ---------------- P2 ----------------
        if (t + 2 < NT) {
            gload16(&lds[d][0][0][0][0] + wBase, pA0[0]);
            gload16(&lds[d][0][0][0][0] + wBase + 512, pA0[1]);
            gload16(&lds[d][1][1][0][0] + wBase, pB1[0]);
            gload16(&lds[d][1][1][0][0] + wBase + 512, pB1[1]);
        }
        __builtin_amdgcn_s_setprio(1);
#pragma unroll
        for (int m = 0; m < 4; ++m) {
#pragma unroll
            for (int n = 0; n < 2; ++n)
#pragma unroll
                for (int kk = 0; kk < 2; ++kk)
                    acc[m][2 + n] = MFMA16(af[m][kk], bf1[n][kk], acc[m][2 + n]);
            // af[m] dead for Q(0,1): reload with A-half1(t) under the cluster
#pragma unroll
            for (int kk = 0; kk < 2; ++kk)
                af[m][kk] = *(const short8*)(&lds[d][0][1][0][0] + offA[m][kk]);
        }
        __builtin_amdgcn_s_setprio(0);

        // ---------------- P3 ----------------
        __builtin_amdgcn_s_setprio(1);
#pragma unroll
        for (int m = 0; m < 4; ++m)
#pragma unroll
            for (int n = 0; n < 2; ++n)
#pragma unroll
                for (int kk = 0; kk < 2; ++kk)
                    acc[4 + m][2 + n] = MFMA16(af[m][kk], bf1[n][kk], acc[4 + m][2 + n]);
        __builtin_amdgcn_s_setprio(0);

        // ---------------- P4 ----------------
        if (t + 2 < NT) {
            asm volatile("s_waitcnt vmcnt(4)" ::: "memory");
        } else if (t + 1 < NT) {
            asm volatile("s_waitcnt vmcnt(0)" ::: "memory");
        }
        __builtin_amdgcn_s_barrier();   // B2
        CFENCE;
        if (t + 2 < NT) {
            gload16(&lds[d][0][1][0][0] + wBase, pA1[0]);
            gload16(&lds[d][0][1][0][0] + wBase + 512, pA1[1]);
        }
        if (t + 1 < NT) {
            // prefetch bf1(t+1) at cluster start (bf1 dead after P3)
#pragma unroll
            for (int n = 0; n < 2; ++n)
#pragma unroll
                for (int kk = 0; kk < 2; ++kk)
                    bf1[n][kk] = *(const short8*)(&lds[d ^ 1][1][1][0][0] + offB[n][kk]);
            __builtin_amdgcn_s_setprio(1);
#pragma unroll
            for (int m = 0; m < 4; ++m) {
#pragma unroll
                for (int n = 0; n < 2; ++n)
#pragma unroll
                    for (int kk = 0; kk < 2; ++kk)
                        acc[4 + m][n] = MFMA16(af[m][kk], bf0[n][kk], acc[4 + m][n]);
                // af[m] dead: reload with A-half0(t+1) under the cluster
#pragma unroll
                for (int kk = 0; kk < 2; ++kk)
                    af[m][kk] = *(const short8*)(&lds[d ^ 1][0][0][0][0] + offA[m][kk]);
            }
            __builtin_amdgcn_s_setprio(0);
        } else {
            __builtin_amdgcn_s_setprio(1);
#pragma unroll
            for (int m = 0; m < 4; ++m)
#pragma unroll
                for (int n = 0; n < 2; ++n)
#pragma unroll
                    for (int kk = 0; kk < 2; ++kk)
                        acc[4 + m][n] = MFMA16(af[m][kk], bf0[n][kk], acc[4 + m][n]);
            __builtin_amdgcn_s_setprio(0);
        }
#pragma unroll
        for (int i = 0; i < 2; ++i) {
            pB0[i] += 64;
            pA0[i] += 64;
            pB1[i] += 64;
            pA1[i] += 64;
        }
        CFENCE;
    }

    // ---- epilogue: C/D layout col=lane&15, row=(lane>>4)*4+reg ----
    const int rBase = tm * 256 + wm * 128;
    const int cBase = tn * 256 + wn * 64;
    const int rOff = (lane >> 4) * 4;
    const int cOff = lane & 15;
    float rs[8][4];
    if (EP == 0) {
#pragma unroll
        for (int m = 0; m < 8; ++m)
#pragma unroll
            for (int r = 0; r < 4; ++r) rs[m][r] = 0.f;
    }
#pragma unroll
    for (int m = 0; m < 8; ++m) {
#pragma unroll
        for (int n = 0; n < 4; ++n) {
            const int col = cBase + n * 16 + cOff;
            if (EP == 0) {
                float bv = bias[col];
#pragma unroll
                for (int r = 0; r < 4; ++r) {
                    int row = rBase + m * 16 + rOff + r;
                    float e = __expf(acc[m][n][r] + bv);
                    rs[m][r] += e;
                    Pout[(long long)row * N + col] = f2bf(e);
                }
            } else {
#pragma unroll
                for (int r = 0; r < 4; ++r) {
                    int row = rBase + m * 16 + rOff + r;
                    Cout[(long long)row * N + col] = acc[m][n][r] * (1.0f / rsum[row]);
                }
            }
        }
    }
    if (EP == 0) {
        // reduce over the 16 lanes (cOff) sharing each row group
#pragma unroll
        for (int m = 0; m < 8; ++m)
#pragma unroll
            for (int r = 0; r < 4; ++r) {
                float s = rs[m][r];
#pragma unroll
                for (int mk = 1; mk < 16; mk <<= 1) s += __shfl_xor(s, mk, 64);
                if ((lane & 15) == 0) red[wn][wm][m * 16 + rOff + r] = s;
            }
        __syncthreads();
        if (tid < 256) {
            int wmm = tid >> 7, rr = tid & 127;
            float s = red[0][wmm][rr] + red[1][wmm][rr] +
                      red[2][wmm][rr] + red[3][wmm][rr];
            Lp[(long long)tn * M + tm * 256 + wmm * 128 + rr] = s;
        }
    }
}

extern "C" void kernel_launch(void* const* d_in, const int* in_sizes, int n_in,
                              void* d_out, int out_size, void* d_ws, size_t ws_size,
                              hipStream_t stream) {
    const float* x = (const float*)d_in[0];   // [2,2048,1024]
    const float* W = (const float*)d_in[1];   // [32000,1024]
    const float* b = (const float*)d_in[2];   // [32000]
    const float* E = (const float*)d_in[3];   // [32000,4096]
    float* out = (float*)d_out;               // [2,2048,4096]

    const int M = 4096, K1 = 1024, V = 32000, N2 = 4096;
    const int NTN1 = V / 256;                 // 125 tn tiles in GEMM1

    char* ws = (char*)d_ws;
    size_t off = 0;
    u16* xb = (u16*)(ws + off); off += (size_t)M * K1 * 2;
    u16* Wb = (u16*)(ws + off); off += (size_t)V * K1 * 2;
    u16* Et = (u16*)(ws + off); off += (size_t)N2 * V * 2;
    u16* P  = (u16*)(ws + off); off += (size_t)M * V * 2;
    float* l  = (float*)(ws + off); off += (size_t)M * 4;
    float* Lp = (float*)(ws + off); off += (size_t)NTN1 * M * 4;

    cast_kernel<<<2048, 256, 0, stream>>>(x, xb, M * K1 / 4);
    cast_kernel<<<2048, 256, 0, stream>>>(W, Wb, V * K1 / 4);
    transpose_cast<<<dim3(N2 / 64, V / 64), 256, 0, stream>>>(E, Et);
    // GEMM1: [4096 x 32000 x 1024] -> P = exp(x@W^T + b) bf16, + row partials
    gemm8p<0><<<(M / 256) * (V / 256), 512, 0, stream>>>(xb, Wb, M, V, K1, b, P, nullptr, nullptr, Lp);
    rowsum2<<<M / 256, 256, 0, stream>>>(Lp, l, M, NTN1);
    // GEMM2: [4096 x 4096 x 32000] -> out = (P/l) @ Et^T, f32
    gemm8p<1><<<(M / 256) * (N2 / 256), 512, 0, stream>>>(P, Et, M, N2, V, nullptr, nullptr, l, out, nullptr);
}